// Round 10
// baseline (160.497 us; speedup 1.0000x reference)
//
#include <hip/hip_runtime.h>
#include <stdint.h>

#define KD 256
#define NO 256
#define NE 16
#define BM 128          // rows per block (4 row-quarter waves x 32)
#define BN 64           // cols per block (2 col-slice waves x 32)
#define XROW 264        // X stage row stride (shorts): 256 + 8 pad
#define GROW 132        // gate_t row stride (floats); 128 rows used

typedef short bf16x8 __attribute__((ext_vector_type(8)));
typedef float f32x4 __attribute__((ext_vector_type(4)));

__device__ __forceinline__ unsigned short f2bf(float f) {
  uint32_t u = __float_as_uint(f);
  u += 0x7fffu + ((u >> 16) & 1u);   // RNE (finite inputs)
  return (unsigned short)(u >> 16);
}
__device__ __forceinline__ float bf2f(unsigned short h) {
  return __uint_as_float(((uint32_t)h) << 16);
}
// gelu(h) = h * sigmoid(h*(1.5957691 + 0.0713548 h^2))  (tanh form)
__device__ __forceinline__ float gelu_f(float h) {
#if __has_builtin(__builtin_amdgcn_exp2f)
  float zn = h * fmaf(-0.10294817f, h * h, -2.3022077f);   // -z*log2(e)
  return h * __builtin_amdgcn_rcpf(1.0f + __builtin_amdgcn_exp2f(zn));
#else
  float z = h * fmaf(0.07135481627f, h * h, 1.5957691216f);
  return h * __builtin_amdgcn_rcpf(1.0f + __expf(-z));
#endif
}

// ---- prep: wave-parallel direct pack (R8, proven). Wf layout unchanged:
// element We[e][kc*32+(lane>>4)*8+i][ob*16+(lane&15)] at
// Wf[(((e*8+kc)*16+ob)*64+lane)*8 + i].
__global__ void moe_prep(const float* __restrict__ We, unsigned short* __restrict__ Wf,
                         const float* __restrict__ Wg, unsigned short* __restrict__ Wgt)
{
  const int tid = threadIdx.x;
  const int bid = blockIdx.x;
  const int w = tid >> 6, lane = tid & 63;
  const int g = bid * 4 + w;                 // 2048 tasks = 16e x 8kc x 16ob
  const int e = g >> 7, kc = (g >> 4) & 7, ob = g & 15;
  const int q = lane >> 4, ln = lane & 15;

  const float* src = We + ((size_t)e * KD + kc * 32 + q * 8) * NO + ob * 16 + ln;
  unsigned int pk[4];
#pragma unroll
  for (int h = 0; h < 4; ++h) {
    unsigned short lo = f2bf(src[(h * 2 + 0) * NO]);
    unsigned short hi = f2bf(src[(h * 2 + 1) * NO]);
    pk[h] = (unsigned int)lo | ((unsigned int)hi << 16);
  }
  uint4* dst = (uint4*)(Wf + ((((size_t)(e * 8 + kc) * 16 + ob) * 64) + lane) * 8);
  *dst = make_uint4(pk[0], pk[1], pk[2], pk[3]);

  if (bid == 0) {   // Wgt: tiny (8 KB), block 0 tail
    int d = tid;
    const float* wr = Wg + (size_t)d * NE;
#pragma unroll
    for (int ee = 0; ee < NE; ++ee)
      Wgt[ee * KD + d] = f2bf(wr[ee]);
  }
}

// ---- main v10: B-traffic reduction via tall tile + B-sharing waves.
// Finding (R0-R9): matrix-pipe busy is CONSTANT 13.4 us (= MFMA floor) in
// every variant; the invariant 55.5 us tracks the 512 MB of per-launch
// B-weight reads from L2 (zero reuse: each line read by one wave of one
// block). R5 corroborates: 2x traffic -> +21%.
// Fix: BM=128 x BN=64 tiles, 8 waves = 4 row-quarters x 2 col-slices.
// Block-uniform expert order (eoff = bid&15): the 4 rq-waves of a cs issue
// IDENTICAL B loads in the same window -> L1/MSHR merge -> L2 B-traffic
// halves (256 MB). Per-wave regs ~180 (a[2][8]=64) -> 2 blocks/CU =
// 4 waves/SIMD (2x R0's TLP, with LESS traffic — unlike R5).
// Inner loop / math chain is R0-exact shrunk: bit-identical output.
__launch_bounds__(512, 4)
__global__ void moe_main(const float* __restrict__ x,
                         const uint4* __restrict__ Wf,
                         const unsigned short* __restrict__ Wgt,
                         const float* __restrict__ be,
                         const float* __restrict__ bg,
                         float* __restrict__ out)
{
  __shared__ __align__(16) unsigned short Xs[BM * XROW];  // 67584 B
  __shared__ __align__(16) float gate_t[NE * GROW];        // 8448 B
  __shared__ unsigned short be_h[NE * BN];                 // 2048 B  (total 78080 B)

  const int tid = threadIdx.x;
  const int bid = blockIdx.x;
  const int n0 = (bid & 3) * BN;             // col quarter
  const int m0 = (bid >> 2) * BM;            // row tile
  const int w = tid >> 6, lane = tid & 63;
  const int rq = w >> 1;                     // row quarter 0..3 (rows rq*32..+31)
  const int cs = w & 1;                      // col slice 0..1 (cols cs*32..+31)
  const int ln = lane & 15, quad = lane >> 4;
  // BLOCK-uniform expert rotation: all 8 waves walk experts in the same order
  // so the 4 rq-waves of each cs-slice read the same B lines together.
  const int eoff = __builtin_amdgcn_readfirstlane(bid & 15);

  // per-wave fragment offset (uint4 units); frag j at +j*64 (=1024 B imm)
  const int voff = ((bid & 3) * 4 + cs * 2) * 64 + lane;

  // ---- stage X tile fp32 -> bf16 (128 rows, all 512 threads)
  {
    const float4* xg = (const float4*)x + (size_t)m0 * (KD / 4);
#pragma unroll
    for (int p = 0; p < 16; ++p) {
      int idx = p * 512 + tid;
      int r = idx >> 6, c = idx & 63;
      float4 v = xg[r * (KD / 4) + c];
      uint32_t lo = (uint32_t)f2bf(v.x) | ((uint32_t)f2bf(v.y) << 16);
      uint32_t hi = (uint32_t)f2bf(v.z) | ((uint32_t)f2bf(v.w) << 16);
      *(uint2*)&Xs[r * XROW + c * 4] = make_uint2(lo, hi);
    }
  }
  // ---- ring fill: slots 0..3 = expert eoff, kc 0..3
  uint4 b[4][2];
#pragma unroll
  for (int kc = 0; kc < 4; ++kc) {
    const uint4* p = Wf + ((size_t)eoff * 8 + kc) * 1024 + voff;
    b[kc][0] = p[0]; b[kc][1] = p[64];
  }
  // ---- stage bias (bf16; |be|<=1/16 -> error ~1e-4)
#pragma unroll
  for (int p = 0; p < 2; ++p) {
    int idx = p * 512 + tid;
    int e = idx >> 6, c = idx & 63;
    be_h[e * BN + c] = f2bf(be[e * NO + n0 + c]);
  }
  __syncthreads();

  // ---- A fragments (32 rows x K=256 per wave): 16 frags, loaded ONCE
  bf16x8 a[2][8];
#pragma unroll
  for (int i = 0; i < 2; ++i)
#pragma unroll
    for (int kc = 0; kc < 8; ++kc)
      a[i][kc] = *(const bf16x8*)&Xs[(rq * 32 + i * 16 + ln) * XROW + kc * 32 + quad * 8];

  // ---- gate: wave w computes rows w*16..w*16+15 for all 16 experts (lane ln = expert)
  {
    f32x4 g = {0.f, 0.f, 0.f, 0.f};
#pragma unroll
    for (int kc = 0; kc < 8; ++kc) {
      bf16x8 af = *(const bf16x8*)&Xs[(w * 16 + ln) * XROW + kc * 32 + quad * 8];
      bf16x8 wb = *(const bf16x8*)(Wgt + (size_t)ln * KD + kc * 32 + quad * 8);
      g = __builtin_amdgcn_mfma_f32_16x16x32_bf16(af, wb, g, 0, 0, 0);
    }
    float bgl = bg[ln];
#pragma unroll
    for (int r = 0; r < 4; ++r) {
      float v = g[r] + bgl;
      float mx = v;
#pragma unroll
      for (int msk = 1; msk < 16; msk <<= 1)
        mx = fmaxf(mx, __shfl_xor(mx, msk, 64));
      float ev = __expf(v - mx);
      float s = ev;
#pragma unroll
      for (int msk = 1; msk < 16; msk <<= 1)
        s += __shfl_xor(s, msk, 64);
      gate_t[ln * GROW + w * 16 + quad * 4 + r] = ev * __builtin_amdgcn_rcpf(s);
    }
  }
  __syncthreads();  // gate_t visible; last barrier in the kernel

  f32x4 acc[2][2], oacc[2][2];
#pragma unroll
  for (int i = 0; i < 2; ++i)
#pragma unroll
    for (int j = 0; j < 2; ++j) {
      acc[i][j] = (f32x4){0.f, 0.f, 0.f, 0.f};
      oacc[i][j] = (f32x4){0.f, 0.f, 0.f, 0.f};
    }

#pragma unroll 1
  for (int ei = 0; ei < NE; ++ei) {
    const int e  = (eoff + ei) & 15;        // block-uniform current expert
    const int en = (eoff + ei + 1) & 15;    // next expert
    const uint4* bse = Wf + (size_t)e  * 8192 + voff;
    const uint4* bsn = Wf + (size_t)en * 8192 + voff;

#pragma unroll
    for (int kc = 0; kc < 8; ++kc) {
      uint4* bc = b[kc & 3];
#pragma unroll
      for (int i = 0; i < 2; ++i)
#pragma unroll
        for (int j = 0; j < 2; ++j)
          acc[i][j] = __builtin_amdgcn_mfma_f32_16x16x32_bf16(
              a[i][kc], *(const bf16x8*)&bc[j], acc[i][j], 0, 0, 0);
      // refill the slot just consumed with set 4 ahead
      if (kc < 4) {
        const uint4* p = bse + (kc + 4) * 1024;
        bc[0] = p[0]; bc[1] = p[64];
      } else if (ei < NE - 1) {
        const uint4* p = bsn + (kc - 4) * 1024;
        bc[0] = p[0]; bc[1] = p[64];
      }
    }
    // ---- expert epilogue: bias + gelu + gate-weighted accumulate (R0-exact)
    {
      f32x4 gv[2];
#pragma unroll
      for (int i = 0; i < 2; ++i)
        gv[i] = *(const f32x4*)&gate_t[e * GROW + rq * 32 + i * 16 + quad * 4];
      const float bb0 = bf2f(be_h[e * BN + cs * 32 + ln]);
      const float bb1 = bf2f(be_h[e * BN + cs * 32 + 16 + ln]);
#pragma unroll
      for (int i = 0; i < 2; ++i)
#pragma unroll
        for (int j = 0; j < 2; ++j)
#pragma unroll
          for (int r = 0; r < 4; ++r) {
            float hh = acc[i][j][r] + (j ? bb1 : bb0);
            oacc[i][j][r] = fmaf(gv[i][r], gelu_f(hh), oacc[i][j][r]);
            acc[i][j][r] = 0.f;
          }
    }
  }

  // ---- store (each out element owned by exactly one wave)
#pragma unroll
  for (int i = 0; i < 2; ++i)
#pragma unroll
    for (int r = 0; r < 4; ++r) {
      int row = m0 + rq * 32 + i * 16 + quad * 4 + r;
      float* orow = out + (size_t)row * NO + n0 + cs * 32 + ln;
      orow[0]  = oacc[i][0][r];
      orow[16] = oacc[i][1][r];
    }
}

extern "C" void kernel_launch(void* const* d_in, const int* in_sizes, int n_in,
                              void* d_out, int out_size, void* d_ws, size_t ws_size,
                              hipStream_t stream) {
  const float* x  = (const float*)d_in[0];
  const float* We = (const float*)d_in[1];
  const float* be = (const float*)d_in[2];
  const float* Wg = (const float*)d_in[3];
  const float* bg = (const float*)d_in[4];
  float* out = (float*)d_out;
  unsigned short* Wf  = (unsigned short*)d_ws;                                      // 2 MB bf16, fragment-ordered
  unsigned short* Wgt = (unsigned short*)((char*)d_ws + (size_t)NE * NO * KD * 2);  // 8 KB bf16 [E][D]

  moe_prep<<<512, 256, 0, stream>>>(We, Wf, Wg, Wgt);
  moe_main<<<512, 512, 0, stream>>>(x, (const uint4*)Wf, Wgt, be, bg, out);
}

// Round 11
// 129.970 us; speedup vs baseline: 1.2349x; 1.2349x over previous
//
#include <hip/hip_runtime.h>
#include <stdint.h>

#define KD 256
#define NO 256
#define NE 16
#define BM 64
#define BN 128
#define XROW 264        // X stage row stride (shorts): 256 + 8 pad
#define GROW 68         // gate_t row stride (floats)

typedef short bf16x8 __attribute__((ext_vector_type(8)));
typedef float f32x4 __attribute__((ext_vector_type(4)));
typedef float f32x2 __attribute__((ext_vector_type(2)));
typedef float f32x16 __attribute__((ext_vector_type(16)));

__device__ __forceinline__ unsigned short f2bf(float f) {
  uint32_t u = __float_as_uint(f);
  u += 0x7fffu + ((u >> 16) & 1u);   // RNE (finite inputs)
  return (unsigned short)(u >> 16);
}
__device__ __forceinline__ float bf2f(unsigned short h) {
  return __uint_as_float(((uint32_t)h) << 16);
}
// gelu*gate accumulate on f32x2 so the backend can emit v_pk_{mul,add,fma}_f32.
// Value-identical chain to R0's scalar gelu_f (same constants, same op order).
__device__ __forceinline__ void epi_pair(f32x2 h, f32x2 gv, f32x2& o) {
  f32x2 t = h * h;
  f32x2 s = __builtin_elementwise_fma(t, (f32x2){-0.10294817f, -0.10294817f},
                                      (f32x2){-2.3022077f, -2.3022077f});
  f32x2 zn = h * s;
  f32x2 ev;
  ev.x = __builtin_amdgcn_exp2f(zn.x);
  ev.y = __builtin_amdgcn_exp2f(zn.y);
  f32x2 den = ev + 1.0f;
  f32x2 r;
  r.x = __builtin_amdgcn_rcpf(den.x);
  r.y = __builtin_amdgcn_rcpf(den.y);
  f32x2 g = h * r;
  o = __builtin_elementwise_fma(gv, g, o);
}

// ---- prep v3: Wf reordered for mfma_f32_32x32x16_bf16.
// Wf32 layout: [e][kk(0..15)][ob2(0..7)][lane(0..63)][i(0..7)] bf16, element =
// We[e][ kk*16 + (lane>>5)*8 + i ][ ob2*32 + (lane&31) ].
// 2048 tasks = 16e x 16kk x 8ob2; one wave per task (R8's proven parallel form).
__global__ void moe_prep(const float* __restrict__ We, unsigned short* __restrict__ Wf,
                         const float* __restrict__ Wg, unsigned short* __restrict__ Wgt)
{
  const int tid = threadIdx.x;
  const int bid = blockIdx.x;
  const int w = tid >> 6, lane = tid & 63;
  const int g = bid * 4 + w;
  const int e = g >> 7, kk = (g >> 3) & 15, ob2 = g & 7;
  const int q5 = lane >> 5, c = lane & 31;

  const float* src = We + ((size_t)e * KD + kk * 16 + q5 * 8) * NO + ob2 * 32 + c;
  unsigned int pk[4];
#pragma unroll
  for (int h = 0; h < 4; ++h) {
    unsigned short lo = f2bf(src[(h * 2 + 0) * NO]);
    unsigned short hi = f2bf(src[(h * 2 + 1) * NO]);
    pk[h] = (unsigned int)lo | ((unsigned int)hi << 16);
  }
  uint4* dst = (uint4*)(Wf + ((((size_t)(e * 16 + kk) * 8 + ob2) * 64) + lane) * 8);
  *dst = make_uint4(pk[0], pk[1], pk[2], pk[3]);

  if (bid == 0) {   // Wgt: tiny (8 KB), block 0 tail (gate stays 16x16 path)
    int d = tid;
    const float* wr = Wg + (size_t)d * NE;
#pragma unroll
    for (int ee = 0; ee < NE; ++ee)
      Wgt[ee * KD + d] = f2bf(wr[ee]);
  }
}

// ---- main v11: R0 skeleton, MFMA shape 16x16x32 -> 32x32x16 (half the
// instructions, -17% matrix-pipe cycles per the 2382-vs-2075 TF ubenches)
// + packed-f32 epilogue. Everything else (tile, waves, ring slack, rotation,
// occupancy, register budget) is R0-identical.
// Layouts (HW-verified m74/m101): A row=lane&31, k=(lane>>5)*8+i;
// B col=lane&31, same k; C/D col=lane&31, row=(reg&3)+8*(reg>>2)+4*(lane>>5).
__launch_bounds__(256, 2)
__global__ void moe_main(const float* __restrict__ x,
                         const uint4* __restrict__ Wf,
                         const unsigned short* __restrict__ Wgt,
                         const float* __restrict__ be,
                         const float* __restrict__ bg,
                         float* __restrict__ out)
{
  __shared__ __align__(16) unsigned short Xs[BM * XROW];  // 33792 B
  __shared__ __align__(16) float gate_t[NE * GROW];        // 4352 B
  __shared__ unsigned short be_h[NE * BN];                 // 4096 B

  const int tid = threadIdx.x;
  const int bid = blockIdx.x;
  const int half = bid & 1;
  const int n0 = half * BN;
  const int m0 = (bid >> 1) * BM;
  const int w = tid >> 6, lane = tid & 63;   // wave w owns cols w*32..w*32+31
  const int ln = lane & 15, quad = lane >> 4;   // gate path (16x16)
  const int c31 = lane & 31, q5 = lane >> 5;    // main path (32x32)
  // per-wave expert rotation, scalarized so refill addresses stay SGPR-based
  const int eoff = __builtin_amdgcn_readfirstlane(((tid >> 6) * 4 + bid) & 15);

  // per-wave B offset (uint4 units): ob2 = half*4 + w, within k-step frame
  const int voff = (half * 4 + w) * 64 + lane;

  // ---- stage X tile fp32 -> bf16
  {
    const float4* xg = (const float4*)x + (size_t)m0 * (KD / 4);
#pragma unroll
    for (int p = 0; p < 16; ++p) {
      int idx = p * 256 + tid;
      int r = idx >> 6, c = idx & 63;
      float4 v = xg[r * (KD / 4) + c];
      uint32_t lo = (uint32_t)f2bf(v.x) | ((uint32_t)f2bf(v.y) << 16);
      uint32_t hi = (uint32_t)f2bf(v.z) | ((uint32_t)f2bf(v.w) << 16);
      *(uint2*)&Xs[r * XROW + c * 4] = make_uint2(lo, hi);
    }
  }
  // ---- ring fill: slots 0..7 = expert eoff, k-steps 0..7 (16 B/lane each)
  uint4 b2[8];
#pragma unroll
  for (int kk = 0; kk < 8; ++kk)
    b2[kk] = Wf[(size_t)eoff * 8192 + kk * 512 + voff];
  // ---- stage bias (bf16; |be|<=1/16 -> error ~1e-4)
#pragma unroll
  for (int p = 0; p < 8; ++p) {
    int idx = p * 256 + tid;
    int e = idx >> 7, c = idx & 127;
    be_h[e * BN + c] = f2bf(be[e * NO + n0 + c]);
  }
  __syncthreads();

  // ---- A fragments for 32x32x16: a[t][kk], t = row-tile (rows t*32..+31),
  // kk = k-step (16 wide). Lane reads X[t*32 + c31][kk*16 + q5*8 .. +7] —
  // contiguous 16 B, same one-time LDS cost as R0's init. 128 regs (AGPR-able).
  bf16x8 a[2][16];
#pragma unroll
  for (int t = 0; t < 2; ++t)
#pragma unroll
    for (int kk = 0; kk < 16; ++kk)
      a[t][kk] = *(const bf16x8*)&Xs[(t * 32 + c31) * XROW + kk * 16 + q5 * 8];

  // ---- gate (unchanged 16x16 path): wave w computes rows w*16..+15, lane ln = expert
  {
    f32x4 g = {0.f, 0.f, 0.f, 0.f};
#pragma unroll
    for (int kc = 0; kc < 8; ++kc) {
      bf16x8 af = *(const bf16x8*)&Xs[(w * 16 + ln) * XROW + kc * 32 + quad * 8];
      bf16x8 wb = *(const bf16x8*)(Wgt + (size_t)ln * KD + kc * 32 + quad * 8);
      g = __builtin_amdgcn_mfma_f32_16x16x32_bf16(af, wb, g, 0, 0, 0);
    }
    float bgl = bg[ln];
#pragma unroll
    for (int r = 0; r < 4; ++r) {
      float v = g[r] + bgl;
      float mx = v;
#pragma unroll
      for (int msk = 1; msk < 16; msk <<= 1)
        mx = fmaxf(mx, __shfl_xor(mx, msk, 64));
      float ev = __expf(v - mx);
      float s = ev;
#pragma unroll
      for (int msk = 1; msk < 16; msk <<= 1)
        s += __shfl_xor(s, msk, 64);
      gate_t[ln * GROW + w * 16 + quad * 4 + r] = ev * __builtin_amdgcn_rcpf(s);
    }
  }
  __syncthreads();  // gate_t visible; last barrier in the kernel

  f32x16 acc2[2], oacc2[2];
#pragma unroll
  for (int t = 0; t < 2; ++t) {
#pragma unroll
    for (int r = 0; r < 16; ++r) { acc2[t][r] = 0.f; oacc2[t][r] = 0.f; }
  }

#pragma unroll 1
  for (int ei = 0; ei < NE; ++ei) {
    const int e  = (eoff + ei) & 15;        // this wave's current expert (scalar)
    const int en = (eoff + ei + 1) & 15;    // next expert (scalar)
    const uint4* bse = Wf + (size_t)e  * 8192 + voff;
    const uint4* bsn = Wf + (size_t)en * 8192 + voff;

#pragma unroll
    for (int kk = 0; kk < 16; ++kk) {
      const bf16x8 bw = *(const bf16x8*)&b2[kk & 7];
#pragma unroll
      for (int t = 0; t < 2; ++t)
        acc2[t] = __builtin_amdgcn_mfma_f32_32x32x16_bf16(
            a[t][kk], bw, acc2[t], 0, 0, 0);
      // refill slot just consumed with k-step 8 ahead (R0-equivalent slack)
      if (kk < 8) {
        b2[kk] = bse[(kk + 8) * 512];
      } else if (ei < NE - 1) {
        b2[kk & 7] = bsn[(kk - 8) * 512];
      }
    }
    // ---- expert epilogue: bias + gelu + gate (packed f32 pairs).
    // Row of acc2[t][reg] = t*32 + (reg&3) + 8*(reg>>2) + 4*q5; col = c31.
    {
      const float bb = bf2f(be_h[e * BN + w * 32 + c31]);
      const f32x2 bb2 = {bb, bb};
#pragma unroll
      for (int t = 0; t < 2; ++t)
#pragma unroll
        for (int rg = 0; rg < 4; ++rg) {
          const f32x4 gq = *(const f32x4*)&gate_t[e * GROW + t * 32 + rg * 8 + q5 * 4];
          f32x2 h0 = {acc2[t][rg * 4 + 0], acc2[t][rg * 4 + 1]};
          f32x2 h1 = {acc2[t][rg * 4 + 2], acc2[t][rg * 4 + 3]};
          h0 = h0 + bb2;
          h1 = h1 + bb2;
          f32x2 o0 = {oacc2[t][rg * 4 + 0], oacc2[t][rg * 4 + 1]};
          f32x2 o1 = {oacc2[t][rg * 4 + 2], oacc2[t][rg * 4 + 3]};
          epi_pair(h0, (f32x2){gq[0], gq[1]}, o0);
          epi_pair(h1, (f32x2){gq[2], gq[3]}, o1);
          oacc2[t][rg * 4 + 0] = o0.x; oacc2[t][rg * 4 + 1] = o0.y;
          oacc2[t][rg * 4 + 2] = o1.x; oacc2[t][rg * 4 + 3] = o1.y;
          acc2[t][rg * 4 + 0] = 0.f; acc2[t][rg * 4 + 1] = 0.f;
          acc2[t][rg * 4 + 2] = 0.f; acc2[t][rg * 4 + 3] = 0.f;
        }
    }
  }

  // ---- store: row = m0 + t*32 + rg*8 + q5*4 + r, col = n0 + w*32 + c31
#pragma unroll
  for (int t = 0; t < 2; ++t)
#pragma unroll
    for (int rg = 0; rg < 4; ++rg)
#pragma unroll
      for (int r = 0; r < 4; ++r) {
        int row = m0 + t * 32 + rg * 8 + q5 * 4 + r;
        out[(size_t)row * NO + n0 + w * 32 + c31] = oacc2[t][rg * 4 + r];
      }
}

extern "C" void kernel_launch(void* const* d_in, const int* in_sizes, int n_in,
                              void* d_out, int out_size, void* d_ws, size_t ws_size,
                              hipStream_t stream) {
  const float* x  = (const float*)d_in[0];
  const float* We = (const float*)d_in[1];
  const float* be = (const float*)d_in[2];
  const float* Wg = (const float*)d_in[3];
  const float* bg = (const float*)d_in[4];
  float* out = (float*)d_out;
  unsigned short* Wf  = (unsigned short*)d_ws;                                      // 2 MB bf16, 32x32-fragment-ordered
  unsigned short* Wgt = (unsigned short*)((char*)d_ws + (size_t)NE * NO * KD * 2);  // 8 KB bf16 [E][D]

  moe_prep<<<512, 256, 0, stream>>>(We, Wf, Wg, Wgt);
  moe_main<<<512, 256, 0, stream>>>(x, (const uint4*)Wf, Wgt, be, bg, out);
}